// Round 7
// baseline (560.568 us; speedup 1.0000x reference)
//
#include <hip/hip_runtime.h>
#include <hip/hip_bf16.h>
#include <math.h>

#define LQ 285
#define LD_S 288
#define ENT_ITERS 50
#define NOUT 99999
#define LDK 72   // 64 k + 8 pad (bf16) -> row stride 144B, 2-way bank alias (free)

typedef __attribute__((ext_vector_type(8))) short bf16x8;
typedef __attribute__((ext_vector_type(4))) float f32x4;

__device__ __forceinline__ float wsum(float v){
  #pragma unroll
  for (int o=32;o;o>>=1) v += __shfl_xor(v,o);
  return v;
}
__device__ __forceinline__ float wmax(float v){
  #pragma unroll
  for (int o=32;o;o>>=1) v = fmaxf(v, __shfl_xor(v,o));
  return v;
}
__device__ __forceinline__ float pfn(float z, float inv){
  return z > 0.f ? exp2f(inv * log2f(z)) : 0.f;
}
__device__ __forceinline__ short f2bf(float f){
  __hip_bfloat16 h = __float2bfloat16(f);
  return *(short*)&h;
}

// ---------------- gather: x_ = concat(emb_w[x], pos_emb_w[pos]), fp32 + bf16 ----------------
__global__ __launch_bounds__(256) void k_gather(const int* __restrict__ x, const int* __restrict__ pos,
    const float* __restrict__ emb, const float* __restrict__ pemb,
    float* __restrict__ xo, short* __restrict__ xbf){
  int bl = blockIdx.x;             // 0..18239
  int d  = threadIdx.x;
  int xi = x[bl], pi = pos[bl];
  float v = (d < 128) ? emb[(size_t)xi*128 + d] : pemb[(size_t)pi*128 + (d-128)];
  xo [(size_t)bl*256 + d] = v;
  xbf[(size_t)bl*256 + d] = f2bf(v);
}

// ---------------- cast 4 weight matrices [256x256] to bf16 ----------------
__global__ __launch_bounds__(256) void k_castw(const float* __restrict__ w0, const float* __restrict__ w1,
    const float* __restrict__ w2, const float* __restrict__ w3, short* __restrict__ dst){
  int idx = blockIdx.x*256 + threadIdx.x;       // 0..262143
  int which = idx >> 16, off = idx & 65535;
  const float* s = which==0 ? w0 : which==1 ? w1 : which==2 ? w2 : w3;
  dst[idx] = f2bf(s[off]);
}

// ---------------- a_ent per batch ----------------
__global__ __launch_bounds__(64) void k_aent(const float* __restrict__ x_, const float* __restrict__ aw,
    const float* __restrict__ ab, float* __restrict__ a_ent){
  int b = blockIdx.x, lane = threadIdx.x;
  const float* r = x_ + ((size_t)b*LQ + (LQ-1))*256;
  float s = 0.f;
  #pragma unroll
  for (int j=0;j<4;++j){ int k = lane + j*64; s = fmaf(r[k], aw[k], s); }
  s = wsum(s);
  if (lane==0){
    float a = 1.f/(1.f + expf(-(s + ab[0]))) + 1.f;
    if (a == 1.f) a = 1.0001f;
    a_ent[b] = a;
  }
}

// ---------------- MFMA bf16 GEMM, 64x64 tile, 4 waves, BK=64 ----------------
// C[M,N] = A[M,K] @ (BT ? B[N,K]^T : B[K,N]); A,B bf16, accum fp32.
// EPI: 0 none | 1 bias+relu | 2 bias+res | 3 scale+key-mask(-inf) | 4 per-row-batch bias + relu
// OF32: write fp32 C; OBF: write bf16 Cbf.
template<bool BT, int EPI, bool OF32, bool OBF>
__global__ __launch_bounds__(256) void k_mgemm(
    const short* __restrict__ A, int lda, long long strA, int kpadA,
    const short* __restrict__ Bm, int ldb, long long strB,
    float* __restrict__ C, short* __restrict__ Cbf, int ldc, long long strC,
    int M, int N, int K,
    const float* __restrict__ bias,
    const float* __restrict__ res,
    const int* __restrict__ xids,
    float scale)
{
  __shared__ __align__(16) short As[64*LDK];
  __shared__ __align__(16) short Bs[64*LDK];
  const int bz = blockIdx.z;
  A  += (size_t)bz * strA;
  Bm += (size_t)bz * strB;
  if (OF32) C   += (size_t)bz * strC;
  if (OBF)  Cbf += (size_t)bz * strC;
  const int* xb = xids ? xids + (size_t)bz*LQ : nullptr;
  const int t  = threadIdx.x;
  const int wv = t >> 6, ln = t & 63;
  const int l16 = ln & 15, kseg = ln >> 4;      // fragment row/col + k-segment
  const int m0 = blockIdx.y*64, n0 = blockIdx.x*64;

  f32x4 acc[4] = {};

  for (int k0 = 0; k0 < K; k0 += 64){
    // --- stage A tile [64 rows][64 k] ---
    #pragma unroll
    for (int it=0; it<2; ++it){
      int idx8 = t + it*256;                    // 0..511
      int r = idx8 >> 3, c8 = (idx8 & 7) << 3;  // row 0..63, k-chunk of 8
      int gr = m0 + r, gk = k0 + c8;
      bf16x8 v = {};
      if (gr < M){
        if (gk + 8 <= kpadA){
          v = *(const bf16x8*)(A + (size_t)gr*lda + gk);
        } else {
          #pragma unroll
          for (int e=0;e<8;++e) if (gk+e < K) v[e] = A[(size_t)gr*lda + gk+e];
        }
      }
      *(bf16x8*)&As[r*LDK + c8] = v;
    }
    // --- stage B tile -> Bs[n][k] ---
    if (BT){
      // B is [N][K] row-major: direct copy
      #pragma unroll
      for (int it=0; it<2; ++it){
        int idx8 = t + it*256;
        int n = idx8 >> 3, c8 = (idx8 & 7) << 3;
        int gn = n0 + n, gk = k0 + c8;
        bf16x8 v = {};
        if (gn < N){
          if (gk + 8 <= K){
            v = *(const bf16x8*)(Bm + (size_t)gn*ldb + gk);
          } else {
            #pragma unroll
            for (int e=0;e<8;++e) if (gk+e < K) v[e] = Bm[(size_t)gn*ldb + gk+e];
          }
        }
        *(bf16x8*)&Bs[n*LDK + c8] = v;
      }
    } else {
      // B is [K][N] row-major: transpose-stage (short2 reads)
      #pragma unroll
      for (int j=0; j<8; ++j){
        int idx2 = t + j*256;                   // 0..2047
        int kk = idx2 >> 5, n2 = (idx2 & 31) << 1;
        int gk = k0 + kk;
        short lo = 0, hi = 0;
        if (gk < K){
          int vv = *(const int*)(Bm + (size_t)gk*ldb + n0 + n2);
          lo = (short)(vv & 0xffff); hi = (short)((unsigned)vv >> 16);
        }
        Bs[(n2  )*LDK + kk] = lo;
        Bs[(n2+1)*LDK + kk] = hi;
      }
    }
    __syncthreads();
    // --- MFMA: wave wv computes rows [wv*16, wv*16+16) x 64 cols ---
    #pragma unroll
    for (int ks=0; ks<64; ks+=32){
      bf16x8 af = *(const bf16x8*)&As[(wv*16 + l16)*LDK + ks + kseg*8];
      #pragma unroll
      for (int ct=0; ct<4; ++ct){
        bf16x8 bf = *(const bf16x8*)&Bs[(ct*16 + l16)*LDK + ks + kseg*8];
        acc[ct] = __builtin_amdgcn_mfma_f32_16x16x32_bf16(af, bf, acc[ct], 0, 0, 0);
      }
    }
    __syncthreads();
  }
  // --- epilogue: C/D layout col=lane&15, row=(lane>>4)*4+i (HW-verified m89/m91) ---
  #pragma unroll
  for (int ct=0; ct<4; ++ct){
    int col = n0 + ct*16 + l16;
    if (col >= N) continue;
    #pragma unroll
    for (int i=0;i<4;++i){
      int row = m0 + wv*16 + kseg*4 + i;
      if (row >= M) continue;
      float v = acc[ct][i];
      if (EPI == 1)      v = fmaxf(v + bias[col], 0.f);
      else if (EPI == 2) v = v + bias[col] + res[(size_t)row*ldc + col];
      else if (EPI == 3){ v *= scale; if (xb[col] == 0) v = -INFINITY; }
      else if (EPI == 4) v = fmaxf(v + bias[(row/LQ)*256 + col], 0.f);
      if (OF32) C  [(size_t)row*ldc + col] = v;
      if (OBF)  Cbf[(size_t)row*ldc + col] = f2bf(v);
    }
  }
}

// ---------------- entmax over 285 keys, one wave per row; fp32 in, bf16 out ----------------
__global__ __launch_bounds__(256) void k_entmax1(const float* __restrict__ att, const float* __restrict__ a_ent,
    short* __restrict__ attbf){
  int wid = blockIdx.x*4 + (threadIdx.x >> 6);
  int lane = threadIdx.x & 63;
  int b = wid / LQ;
  const float* row = att + (size_t)wid * LD_S;
  short* orow = attbf + (size_t)wid * LD_S;
  float alpha = a_ent[b], am1 = alpha - 1.f, inv = 1.f/am1;
  float Xs[5];
  #pragma unroll
  for (int j=0;j<5;++j){ int k = lane + j*64; Xs[j] = (k < LQ) ? row[k]*am1 : -INFINITY; }
  float mx = Xs[0];
  #pragma unroll
  for (int j=1;j<5;++j) mx = fmaxf(mx, Xs[j]);
  mx = wmax(mx);
  float tau_lo = mx - 1.f;
  float tau_hi = mx - exp2f(am1 * log2f(1.f/(float)LQ));
  float s = 0.f;
  #pragma unroll
  for (int j=0;j<5;++j) s += pfn(Xs[j]-tau_lo, inv);
  float f_lo = wsum(s) - 1.f;
  float dm = tau_hi - tau_lo;
  float p[5]; float fsum = 1.f;
  for (int it=0; it<ENT_ITERS; ++it){
    dm *= 0.5f;
    float tau = tau_lo + dm;
    float sl = 0.f;
    #pragma unroll
    for (int j=0;j<5;++j){ float pj = pfn(Xs[j]-tau, inv); p[j]=pj; sl += pj; }
    fsum = wsum(sl);
    if ((fsum - 1.f)*f_lo >= 0.f) tau_lo = tau;
  }
  float rs = 1.f/fsum;
  #pragma unroll
  for (int j=0;j<5;++j){
    int k = lane + j*64;
    if (k < LQ) orow[k] = f2bf(p[j]*rs);
    else if (k < LD_S) orow[k] = 0;   // zero pad: GEMM3 reads through k=287
  }
}

// ---------------- layernorm over 256 (in-place on v2) + bf16 out ----------------
__global__ __launch_bounds__(256) void k_ln(float* __restrict__ v2, const float* __restrict__ g,
    const float* __restrict__ bb, short* __restrict__ obf){
  __shared__ float red[4];
  int r = blockIdx.x, t = threadIdx.x;
  float v = v2[(size_t)r*256 + t];
  float s = wsum(v);
  if ((t&63)==0) red[t>>6] = s;
  __syncthreads();
  float mean = (red[0]+red[1]+red[2]+red[3]) * (1.f/256.f);
  __syncthreads();
  float d = v - mean;
  float ss = wsum(d*d);
  if ((t&63)==0) red[t>>6] = ss;
  __syncthreads();
  float var = (red[0]+red[1]+red[2]+red[3]) * (1.f/256.f);
  float o = d * rsqrtf(var + 1e-5f) * g[t] + bb[t];
  v2[(size_t)r*256 + t] = o;
  obf[(size_t)r*256 + t] = f2bf(o);
}

// ---------------- m_s @ atten_w2 + bias, and a_glob ----------------
__global__ __launch_bounds__(256) void k_msw2(const float* __restrict__ ln, const float* __restrict__ w2,
    const float* __restrict__ abias, const float* __restrict__ aw, const float* __restrict__ ab,
    float* __restrict__ msw2, float* __restrict__ a_glob){
  __shared__ float ms[256];
  __shared__ float red[4];
  int b = blockIdx.x, t = threadIdx.x;
  float m = ln[((size_t)b*LQ + (LQ-1))*256 + t];
  ms[t] = m;
  float s = wsum(m * aw[t]);
  if ((t&63)==0) red[t>>6] = s;
  __syncthreads();
  if (t == 0){
    float dot = red[0]+red[1]+red[2]+red[3] + ab[0];
    float a = 1.f/(1.f + expf(-dot)) + 1.f;
    if (a == 1.f) a = 1.0001f;
    a_glob[b] = a;
  }
  float acc = abias[t];
  for (int d=0; d<256; ++d) acc = fmaf(ms[d], w2[d*256 + t], acc);
  msw2[b*256 + t] = acc;
}

// ---------------- al = t @ atten_w0^T, masked ----------------
__global__ __launch_bounds__(256) void k_al(const float* __restrict__ tbuf, const float* __restrict__ w0,
    const int* __restrict__ x, float* __restrict__ al){
  int wid = blockIdx.x*4 + (threadIdx.x >> 6);
  int lane = threadIdx.x & 63;
  int b = wid / 284, r = wid % 284;
  const float* tr = tbuf + ((size_t)b*LQ + r)*256;
  float s = 0.f;
  #pragma unroll
  for (int j=0;j<4;++j){ int k = lane + j*64; s = fmaf(tr[k], w0[k], s); }
  s = wsum(s);
  if (lane == 0) al[b*284 + r] = (x[b*LQ + r] != 0) ? s : -INFINITY;
}

// ---------------- entmax over 284 + global_c + selu head + l_c ----------------
__global__ __launch_bounds__(256) void k_second(
    const float* __restrict__ al, const float* __restrict__ a_glob,
    const float* __restrict__ x_, const float* __restrict__ ln,
    const float* __restrict__ wfw, const float* __restrict__ wfb,
    float* __restrict__ l_c){
  __shared__ float red[4];
  __shared__ float saw[284];
  __shared__ float gcs[256];
  __shared__ float ms[256];
  __shared__ float cb[128];
  int b = blockIdx.x, t = threadIdx.x;
  float alpha = a_glob[b], am1 = alpha - 1.f, inv = 1.f/am1;
  float X0 = (t < 284) ? al[b*284 + t]*am1 : -INFINITY;
  float X1 = (t < 28)  ? al[b*284 + t + 256]*am1 : -INFINITY;
  float mx = fmaxf(X0, X1);
  mx = wmax(mx);
  if ((t&63)==0) red[t>>6] = mx;
  __syncthreads();
  mx = fmaxf(fmaxf(red[0],red[1]), fmaxf(red[2],red[3]));
  __syncthreads();
  float tau_lo = mx - 1.f;
  float tau_hi = mx - exp2f(am1 * log2f(1.f/284.f));
  float s = pfn(X0 - tau_lo, inv) + pfn(X1 - tau_lo, inv);
  s = wsum(s);
  if ((t&63)==0) red[t>>6] = s;
  __syncthreads();
  float f_lo = (red[0]+red[1]+red[2]+red[3]) - 1.f;
  __syncthreads();
  float dm = tau_hi - tau_lo;
  float p0 = 0.f, p1 = 0.f, fsum = 1.f;
  for (int it=0; it<ENT_ITERS; ++it){
    dm *= 0.5f;
    float tau = tau_lo + dm;
    p0 = pfn(X0 - tau, inv);
    p1 = pfn(X1 - tau, inv);
    float sl = wsum(p0 + p1);
    if ((t&63)==0) red[t>>6] = sl;
    __syncthreads();
    fsum = red[0]+red[1]+red[2]+red[3];
    __syncthreads();
    if ((fsum - 1.f)*f_lo >= 0.f) tau_lo = tau;
  }
  if (t < 284) saw[t] = p0/fsum;
  if (t < 28)  saw[t+256] = p1/fsum;
  __syncthreads();
  float g = 0.f;
  for (int k=0; k<284; ++k) g = fmaf(saw[k], x_[((size_t)b*LQ + k)*256 + t], g);
  gcs[t] = g;
  ms[t]  = ln[((size_t)b*LQ + (LQ-1))*256 + t];
  __syncthreads();
  if (t < 128){
    float acc = wfb[t];
    const float* wr = wfw + (size_t)t*512;
    for (int d=0; d<256; ++d) acc = fmaf(gcs[d], wr[d], acc);
    for (int d=0; d<256; ++d) acc = fmaf(ms[d], wr[256+d], acc);
    const float SC = 1.0507009873554805f, AL = 1.6732632423543772f;
    acc = acc > 0.f ? SC*acc : SC*AL*(expf(acc) - 1.f);
    cb[t] = acc;
  }
  __syncthreads();
  float sq = (t < 128) ? cb[t]*cb[t] : 0.f;
  sq = wsum(sq);
  if ((t&63)==0) red[t>>6] = sq;
  __syncthreads();
  float nrm = rsqrtf(red[0]+red[1]+red[2]+red[3]);
  if (t < 128) l_c[b*128 + t] = cb[t]*nrm;
}

// ---------------- z = 20 * l_c @ normalize(emb_w[1:-1])^T (fp32) ----------------
__global__ __launch_bounds__(256) void k_z(const float* __restrict__ emb, const float* __restrict__ l_c,
    float* __restrict__ z){
  __shared__ float lc[64*128];
  __shared__ float e[64*128];
  __shared__ float invn[64];
  int t = threadIdx.x;
  int i0 = blockIdx.x*64;
  #pragma unroll
  for (int u=0;u<8;++u)
    ((float4*)lc)[t + u*256] = ((const float4*)l_c)[t + u*256];
  #pragma unroll
  for (int pass=0; pass<8; ++pass){
    int r = (t>>5) + pass*8;
    int c = t & 31;
    int gi = i0 + r;
    float4 v = make_float4(0.f,0.f,0.f,0.f);
    if (gi < NOUT) v = ((const float4*)(emb + ((size_t)gi+1)*128))[c];
    ((float4*)e)[r*32 + (c ^ (r&31))] = v;
  }
  __syncthreads();
  {
    int r = t>>2, q = t&3;
    float ss = 0.f;
    #pragma unroll
    for (int u=0;u<8;++u){
      int c = q*8 + u;
      float4 v = ((float4*)e)[r*32 + (c ^ (r&31))];
      ss = fmaf(v.x,v.x, fmaf(v.y,v.y, fmaf(v.z,v.z, fmaf(v.w,v.w, ss))));
    }
    ss += __shfl_xor(ss,1);
    ss += __shfl_xor(ss,2);
    if (q==0) invn[r] = rsqrtf(ss);
  }
  __syncthreads();
  int i = t & 63, bg = t >> 6;
  float inv = invn[i];
  float acc[16];
  #pragma unroll
  for (int u=0;u<16;++u) acc[u]=0.f;
  #pragma unroll 4
  for (int c=0;c<32;++c){
    float4 ev = ((float4*)e)[i*32 + (c ^ (i&31))];
    #pragma unroll
    for (int bb=0; bb<16; ++bb){
      float4 lv = ((float4*)lc)[(bg*16+bb)*32 + c];
      acc[bb] = fmaf(ev.x,lv.x, fmaf(ev.y,lv.y, fmaf(ev.z,lv.z, fmaf(ev.w,lv.w, acc[bb]))));
    }
  }
  int gi = i0 + i;
  if (gi < NOUT){
    float sc = 20.f * inv;
    #pragma unroll
    for (int bb=0; bb<16; ++bb) z[(size_t)(bg*16+bb)*NOUT + gi] = sc*acc[bb];
  }
}

extern "C" void kernel_launch(void* const* d_in, const int* in_sizes, int n_in,
                              void* d_out, int out_size, void* d_ws, size_t ws_size,
                              hipStream_t stream){
  const int*   x          = (const int*)d_in[0];
  const int*   pos        = (const int*)d_in[1];
  const float* emb_w      = (const float*)d_in[2];
  const float* pos_emb_w  = (const float*)d_in[3];
  const float* atten_w0   = (const float*)d_in[4];
  const float* atten_w1   = (const float*)d_in[5];
  const float* atten_w2   = (const float*)d_in[6];
  const float* atten_bias = (const float*)d_in[7];
  const float* mlp_w      = (const float*)d_in[8];
  const float* mlp_b      = (const float*)d_in[9];
  const float* sa_w1_w    = (const float*)d_in[10];
  const float* sa_w1_b    = (const float*)d_in[11];
  const float* sa_w2_w    = (const float*)d_in[12];
  const float* sa_w2_b    = (const float*)d_in[13];
  const float* ln_g       = (const float*)d_in[14];
  const float* ln_b       = (const float*)d_in[15];
  const float* w_f_w      = (const float*)d_in[16];
  const float* w_f_b      = (const float*)d_in[17];
  const float* alpha_w_w  = (const float*)d_in[18];
  const float* alpha_w_b  = (const float*)d_in[19];
  float* z = (float*)d_out;

  float* ws = (float*)d_ws;
  const size_t NX = (size_t)64*LQ*256;   // 4,669,440
  const size_t NS = (size_t)64*LQ*LD_S;  // 5,253,120
  // fp32 region (floats): 3*NX + NS + 43008  ~= 77.2 MB
  float* x_    = ws;                     // [NX] fp32 x_
  float* bq    = ws + NX;                // [NX] t output (fp32)
  float* sc    = ws + 2*NX;              // [NS] scores -> (later) v2/LN in-place
  float* attv  = ws + 2*NX + NS;         // [NX] att_v fp32 (residual)
  float* v2    = sc;                     // alias (scores dead after entmax)
  float* lnb   = v2;                     // alias
  float* small = ws + 3*NX + NS;
  float* a_ent  = small;                 // 64
  float* a_glob = small + 64;            // 64
  float* msw2   = small + 128;           // 16384
  float* albuf  = small + 128 + 16384;   // 64*284
  float* l_c    = albuf + 64*284;        // 8192
  // bf16 region (~48.4 MB). total ws use ~126 MB.
  short* bfbase = (short*)(ws + 3*NX + NS + 43008);
  short* x_bf   = bfbase;                // [NX]
  short* gbf    = bfbase + NX;           // [NX] q_ then h
  short* attbf  = bfbase + 2*NX;         // [NS]
  short* attvbf = attbf + NS;            // [NX]
  short* lnbf   = attvbf + NX;           // [NX]
  short* wbf    = lnbf + NX;             // 4*65536: mlp_w, sa_w1_w, sa_w2_w, atten_w1
  short* w_mlp  = wbf;
  short* w_sa1  = wbf + 65536;
  short* w_sa2  = wbf + 2*65536;
  short* w_aw1  = wbf + 3*65536;

  k_gather<<<18240, 256, 0, stream>>>(x, pos, emb_w, pos_emb_w, x_, x_bf);
  k_castw<<<1024, 256, 0, stream>>>(mlp_w, sa_w1_w, sa_w2_w, atten_w1, wbf);
  k_aent<<<64, 64, 0, stream>>>(x_, alpha_w_w, alpha_w_b, a_ent);
  // q_ = relu(x_ @ mlp_w^T + mlp_b)            -> gbf (bf16 only)
  k_mgemm<true,1,false,true><<<dim3(4,285,1), 256, 0, stream>>>(
      x_bf,256,0,256, w_mlp,256,0, nullptr, gbf,256,0,
      18240,256,256, mlp_b, nullptr, nullptr, 0.f);
  // scores = q_ @ x_^T / 16, key-masked        -> sc (fp32)
  k_mgemm<true,3,true,false><<<dim3(5,5,64), 256, 0, stream>>>(
      gbf,256,(long long)LQ*256,256, x_bf,256,(long long)LQ*256,
      sc, nullptr, LD_S,(long long)LQ*LD_S,
      285,285,256, nullptr, nullptr, x, 0.0625f);
  k_entmax1<<<4560, 256, 0, stream>>>(sc, a_ent, attbf);
  // att_v = att @ x_ (B non-transposed)        -> attv fp32 + attvbf
  k_mgemm<false,0,true,true><<<dim3(4,5,64), 256, 0, stream>>>(
      attbf,LD_S,(long long)LQ*LD_S,LD_S, x_bf,256,(long long)LQ*256,
      attv, attvbf, 256,(long long)LQ*256,
      285,256,285, nullptr, nullptr, nullptr, 0.f);
  // h = relu(att_v @ sa_w1^T + b1)             -> gbf (bf16 only)
  k_mgemm<true,1,false,true><<<dim3(4,285,1), 256, 0, stream>>>(
      attvbf,256,0,256, w_sa1,256,0, nullptr, gbf,256,0,
      18240,256,256, sa_w1_b, nullptr, nullptr, 0.f);
  // v2 = h @ sa_w2^T + b2 + att_v              -> v2 fp32 (aliases sc)
  k_mgemm<true,2,true,false><<<dim3(4,285,1), 256, 0, stream>>>(
      gbf,256,0,256, w_sa2,256,0, v2, nullptr, 256,0,
      18240,256,256, sa_w2_b, attv, nullptr, 0.f);
  k_ln<<<18240, 256, 0, stream>>>(v2, ln_g, ln_b, lnbf);
  k_msw2<<<64, 256, 0, stream>>>(lnb, atten_w2, atten_bias, alpha_w_w, alpha_w_b, msw2, a_glob);
  // t = relu(ln @ atten_w1 + msw2[b]) (B non-transposed) -> bq fp32
  k_mgemm<false,4,true,false><<<dim3(4,285,1), 256, 0, stream>>>(
      lnbf,256,0,256, w_aw1,256,0, bq, nullptr, 256,0,
      18240,256,256, msw2, nullptr, nullptr, 0.f);
  k_al<<<4544, 256, 0, stream>>>(bq, atten_w0, x, albuf);
  k_second<<<64, 256, 0, stream>>>(albuf, a_glob, x_, lnb, w_f_w, w_f_b, l_c);
  k_z<<<1563, 256, 0, stream>>>(emb_w, l_c, z);
}

// Round 8
// 461.796 us; speedup vs baseline: 1.2139x; 1.2139x over previous
//
#include <hip/hip_runtime.h>
#include <hip/hip_bf16.h>
#include <math.h>

#define LQ 285
#define LD_S 288
#define ENT_ITERS 30   // bisection converged below fp32 ulp by ~27; ref's 50 adds nothing
#define NOUT 99999
#define LDK 72   // 64 k + 8 pad (bf16) -> row stride 144B, 2-way bank alias (free)

typedef __attribute__((ext_vector_type(8))) short bf16x8;
typedef __attribute__((ext_vector_type(4))) float f32x4;

__device__ __forceinline__ float wsum(float v){
  #pragma unroll
  for (int o=32;o;o>>=1) v += __shfl_xor(v,o);
  return v;
}
__device__ __forceinline__ float wmax(float v){
  #pragma unroll
  for (int o=32;o;o>>=1) v = fmaxf(v, __shfl_xor(v,o));
  return v;
}
// native v_log_f32 (=log2) + v_exp_f32 (=2^x): single-instruction pow, ~1ulp
__device__ __forceinline__ float pfn(float z, float inv){
  return z > 0.f ? __builtin_amdgcn_exp2f(inv * __builtin_amdgcn_logf(z)) : 0.f;
}
__device__ __forceinline__ short f2bf(float f){
  __hip_bfloat16 h = __float2bfloat16(f);
  return *(short*)&h;
}

// ---------------- gather: x_ = concat(emb_w[x], pos_emb_w[pos]), fp32 + bf16 ----------------
__global__ __launch_bounds__(256) void k_gather(const int* __restrict__ x, const int* __restrict__ pos,
    const float* __restrict__ emb, const float* __restrict__ pemb,
    float* __restrict__ xo, short* __restrict__ xbf){
  int bl = blockIdx.x;             // 0..18239
  int d  = threadIdx.x;
  int xi = x[bl], pi = pos[bl];
  float v = (d < 128) ? emb[(size_t)xi*128 + d] : pemb[(size_t)pi*128 + (d-128)];
  xo [(size_t)bl*256 + d] = v;
  xbf[(size_t)bl*256 + d] = f2bf(v);
}

// ---------------- cast 4 weight matrices [256x256] to bf16 ----------------
__global__ __launch_bounds__(256) void k_castw(const float* __restrict__ w0, const float* __restrict__ w1,
    const float* __restrict__ w2, const float* __restrict__ w3, short* __restrict__ dst){
  int idx = blockIdx.x*256 + threadIdx.x;       // 0..262143
  int which = idx >> 16, off = idx & 65535;
  const float* s = which==0 ? w0 : which==1 ? w1 : which==2 ? w2 : w3;
  dst[idx] = f2bf(s[off]);
}

// ---------------- a_ent per batch ----------------
__global__ __launch_bounds__(64) void k_aent(const float* __restrict__ x_, const float* __restrict__ aw,
    const float* __restrict__ ab, float* __restrict__ a_ent){
  int b = blockIdx.x, lane = threadIdx.x;
  const float* r = x_ + ((size_t)b*LQ + (LQ-1))*256;
  float s = 0.f;
  #pragma unroll
  for (int j=0;j<4;++j){ int k = lane + j*64; s = fmaf(r[k], aw[k], s); }
  s = wsum(s);
  if (lane==0){
    float a = 1.f/(1.f + expf(-(s + ab[0]))) + 1.f;
    if (a == 1.f) a = 1.0001f;
    a_ent[b] = a;
  }
}

// ---------------- MFMA bf16 GEMM, 64x64 tile, 4 waves, BK=64 ----------------
// C[M,N] = A[M,K] @ (BT ? B[N,K]^T : B[K,N]); A,B bf16, accum fp32.
// EPI: 0 none | 1 bias+relu | 2 bias+res | 3 scale+key-mask(-inf) | 4 per-row-batch bias + relu
// OF32: write fp32 C; OBF: write bf16 Cbf.
template<bool BT, int EPI, bool OF32, bool OBF>
__global__ __launch_bounds__(256) void k_mgemm(
    const short* __restrict__ A, int lda, long long strA, int kpadA,
    const short* __restrict__ Bm, int ldb, long long strB,
    float* __restrict__ C, short* __restrict__ Cbf, int ldc, long long strC,
    int M, int N, int K,
    const float* __restrict__ bias,
    const float* __restrict__ res,
    const int* __restrict__ xids,
    float scale)
{
  __shared__ __align__(16) short As[64*LDK];
  __shared__ __align__(16) short Bs[64*LDK];
  const int bz = blockIdx.z;
  A  += (size_t)bz * strA;
  Bm += (size_t)bz * strB;
  if (OF32) C   += (size_t)bz * strC;
  if (OBF)  Cbf += (size_t)bz * strC;
  const int* xb = xids ? xids + (size_t)bz*LQ : nullptr;
  const int t  = threadIdx.x;
  const int wv = t >> 6, ln = t & 63;
  const int l16 = ln & 15, kseg = ln >> 4;      // fragment row/col + k-segment
  const int m0 = blockIdx.y*64, n0 = blockIdx.x*64;

  f32x4 acc[4] = {};

  for (int k0 = 0; k0 < K; k0 += 64){
    // --- stage A tile [64 rows][64 k] ---
    #pragma unroll
    for (int it=0; it<2; ++it){
      int idx8 = t + it*256;                    // 0..511
      int r = idx8 >> 3, c8 = (idx8 & 7) << 3;  // row 0..63, k-chunk of 8
      int gr = m0 + r, gk = k0 + c8;
      bf16x8 v = {};
      if (gr < M){
        if (gk + 8 <= kpadA){
          v = *(const bf16x8*)(A + (size_t)gr*lda + gk);
        } else {
          #pragma unroll
          for (int e=0;e<8;++e) if (gk+e < K) v[e] = A[(size_t)gr*lda + gk+e];
        }
      }
      *(bf16x8*)&As[r*LDK + c8] = v;
    }
    // --- stage B tile -> Bs[n][k] ---
    if (BT){
      // B is [N][K] row-major: direct copy
      #pragma unroll
      for (int it=0; it<2; ++it){
        int idx8 = t + it*256;
        int n = idx8 >> 3, c8 = (idx8 & 7) << 3;
        int gn = n0 + n, gk = k0 + c8;
        bf16x8 v = {};
        if (gn < N){
          if (gk + 8 <= K){
            v = *(const bf16x8*)(Bm + (size_t)gn*ldb + gk);
          } else {
            #pragma unroll
            for (int e=0;e<8;++e) if (gk+e < K) v[e] = Bm[(size_t)gn*ldb + gk+e];
          }
        }
        *(bf16x8*)&Bs[n*LDK + c8] = v;
      }
    } else {
      // B is [K][N] row-major: transpose-stage (short2 reads)
      #pragma unroll
      for (int j=0; j<8; ++j){
        int idx2 = t + j*256;                   // 0..2047
        int kk = idx2 >> 5, n2 = (idx2 & 31) << 1;
        int gk = k0 + kk;
        short lo = 0, hi = 0;
        if (gk < K){
          int vv = *(const int*)(Bm + (size_t)gk*ldb + n0 + n2);
          lo = (short)(vv & 0xffff); hi = (short)((unsigned)vv >> 16);
        }
        Bs[(n2  )*LDK + kk] = lo;
        Bs[(n2+1)*LDK + kk] = hi;
      }
    }
    __syncthreads();
    // --- MFMA: wave wv computes rows [wv*16, wv*16+16) x 64 cols ---
    #pragma unroll
    for (int ks=0; ks<64; ks+=32){
      bf16x8 af = *(const bf16x8*)&As[(wv*16 + l16)*LDK + ks + kseg*8];
      #pragma unroll
      for (int ct=0; ct<4; ++ct){
        bf16x8 bf = *(const bf16x8*)&Bs[(ct*16 + l16)*LDK + ks + kseg*8];
        acc[ct] = __builtin_amdgcn_mfma_f32_16x16x32_bf16(af, bf, acc[ct], 0, 0, 0);
      }
    }
    __syncthreads();
  }
  // --- epilogue: C/D layout col=lane&15, row=(lane>>4)*4+i (HW-verified m89/m91) ---
  #pragma unroll
  for (int ct=0; ct<4; ++ct){
    int col = n0 + ct*16 + l16;
    if (col >= N) continue;
    #pragma unroll
    for (int i=0;i<4;++i){
      int row = m0 + wv*16 + kseg*4 + i;
      if (row >= M) continue;
      float v = acc[ct][i];
      if (EPI == 1)      v = fmaxf(v + bias[col], 0.f);
      else if (EPI == 2) v = v + bias[col] + res[(size_t)row*ldc + col];
      else if (EPI == 3){ v *= scale; if (xb[col] == 0) v = -INFINITY; }
      else if (EPI == 4) v = fmaxf(v + bias[(row/LQ)*256 + col], 0.f);
      if (OF32) C  [(size_t)row*ldc + col] = v;
      if (OBF)  Cbf[(size_t)row*ldc + col] = f2bf(v);
    }
  }
}

// ---------------- entmax over 285 keys, one wave per row; fp32 in, bf16 out ----------------
__global__ __launch_bounds__(256) void k_entmax1(const float* __restrict__ att, const float* __restrict__ a_ent,
    short* __restrict__ attbf){
  int wid = blockIdx.x*4 + (threadIdx.x >> 6);
  int lane = threadIdx.x & 63;
  int b = wid / LQ;
  const float* row = att + (size_t)wid * LD_S;
  short* orow = attbf + (size_t)wid * LD_S;
  float alpha = a_ent[b], am1 = alpha - 1.f, inv = 1.f/am1;
  float Xs[5];
  #pragma unroll
  for (int j=0;j<5;++j){ int k = lane + j*64; Xs[j] = (k < LQ) ? row[k]*am1 : -INFINITY; }
  float mx = Xs[0];
  #pragma unroll
  for (int j=1;j<5;++j) mx = fmaxf(mx, Xs[j]);
  mx = wmax(mx);
  float tau_lo = mx - 1.f;
  float tau_hi = mx - __builtin_amdgcn_exp2f(am1 * __builtin_amdgcn_logf(1.f/(float)LQ));
  float s = 0.f;
  #pragma unroll
  for (int j=0;j<5;++j) s += pfn(Xs[j]-tau_lo, inv);
  float f_lo = wsum(s) - 1.f;
  float dm = tau_hi - tau_lo;
  float p[5]; float fsum = 1.f;
  for (int it=0; it<ENT_ITERS; ++it){
    dm *= 0.5f;
    float tau = tau_lo + dm;
    float sl = 0.f;
    #pragma unroll
    for (int j=0;j<5;++j){ float pj = pfn(Xs[j]-tau, inv); p[j]=pj; sl += pj; }
    fsum = wsum(sl);
    if ((fsum - 1.f)*f_lo >= 0.f) tau_lo = tau;
  }
  float rs = 1.f/fsum;
  #pragma unroll
  for (int j=0;j<5;++j){
    int k = lane + j*64;
    if (k < LQ) orow[k] = f2bf(p[j]*rs);
    else if (k < LD_S) orow[k] = 0;   // zero pad: GEMM3 reads through k=287
  }
}

// ---------------- layernorm over 256 (in-place on v2) + bf16 out ----------------
__global__ __launch_bounds__(256) void k_ln(float* __restrict__ v2, const float* __restrict__ g,
    const float* __restrict__ bb, short* __restrict__ obf){
  __shared__ float red[4];
  int r = blockIdx.x, t = threadIdx.x;
  float v = v2[(size_t)r*256 + t];
  float s = wsum(v);
  if ((t&63)==0) red[t>>6] = s;
  __syncthreads();
  float mean = (red[0]+red[1]+red[2]+red[3]) * (1.f/256.f);
  __syncthreads();
  float d = v - mean;
  float ss = wsum(d*d);
  if ((t&63)==0) red[t>>6] = ss;
  __syncthreads();
  float var = (red[0]+red[1]+red[2]+red[3]) * (1.f/256.f);
  float o = d * rsqrtf(var + 1e-5f) * g[t] + bb[t];
  v2[(size_t)r*256 + t] = o;
  obf[(size_t)r*256 + t] = f2bf(o);
}

// ---------------- m_s @ atten_w2 + bias, and a_glob ----------------
__global__ __launch_bounds__(256) void k_msw2(const float* __restrict__ ln, const float* __restrict__ w2,
    const float* __restrict__ abias, const float* __restrict__ aw, const float* __restrict__ ab,
    float* __restrict__ msw2, float* __restrict__ a_glob){
  __shared__ float ms[256];
  __shared__ float red[4];
  int b = blockIdx.x, t = threadIdx.x;
  float m = ln[((size_t)b*LQ + (LQ-1))*256 + t];
  ms[t] = m;
  float s = wsum(m * aw[t]);
  if ((t&63)==0) red[t>>6] = s;
  __syncthreads();
  if (t == 0){
    float dot = red[0]+red[1]+red[2]+red[3] + ab[0];
    float a = 1.f/(1.f + expf(-dot)) + 1.f;
    if (a == 1.f) a = 1.0001f;
    a_glob[b] = a;
  }
  float acc = abias[t];
  for (int d=0; d<256; ++d) acc = fmaf(ms[d], w2[d*256 + t], acc);
  msw2[b*256 + t] = acc;
}

// ---------------- al = t @ atten_w0^T, masked ----------------
__global__ __launch_bounds__(256) void k_al(const float* __restrict__ tbuf, const float* __restrict__ w0,
    const int* __restrict__ x, float* __restrict__ al){
  int wid = blockIdx.x*4 + (threadIdx.x >> 6);
  int lane = threadIdx.x & 63;
  int b = wid / 284, r = wid % 284;
  const float* tr = tbuf + ((size_t)b*LQ + r)*256;
  float s = 0.f;
  #pragma unroll
  for (int j=0;j<4;++j){ int k = lane + j*64; s = fmaf(tr[k], w0[k], s); }
  s = wsum(s);
  if (lane == 0) al[b*284 + r] = (x[b*LQ + r] != 0) ? s : -INFINITY;
}

// ---------------- entmax over 284 (wave-local, no barriers) + global_c + selu head + l_c ----------------
__global__ __launch_bounds__(256) void k_second(
    const float* __restrict__ al, const float* __restrict__ a_glob,
    const float* __restrict__ x_, const float* __restrict__ ln,
    const float* __restrict__ wfw, const float* __restrict__ wfb,
    float* __restrict__ l_c){
  __shared__ float red[4];
  __shared__ float saw[284];
  __shared__ float gcs[256];
  __shared__ float ms[256];
  __shared__ float cb[128];
  int b = blockIdx.x, t = threadIdx.x;
  int wv = t >> 6, lane = t & 63;
  // --- bisection entirely inside wave 0: 5 elems/lane, shuffle reduce, zero barriers ---
  if (wv == 0){
    float alpha = a_glob[b], am1 = alpha - 1.f, inv = 1.f/am1;
    float Xs[5];
    #pragma unroll
    for (int j=0;j<5;++j){ int k = lane + j*64; Xs[j] = (k < 284) ? al[b*284 + k]*am1 : -INFINITY; }
    float mx = Xs[0];
    #pragma unroll
    for (int j=1;j<5;++j) mx = fmaxf(mx, Xs[j]);
    mx = wmax(mx);
    float tau_lo = mx - 1.f;
    float tau_hi = mx - __builtin_amdgcn_exp2f(am1 * __builtin_amdgcn_logf(1.f/284.f));
    float s = 0.f;
    #pragma unroll
    for (int j=0;j<5;++j) s += pfn(Xs[j]-tau_lo, inv);
    float f_lo = wsum(s) - 1.f;
    float dm = tau_hi - tau_lo;
    float p[5]; float fsum = 1.f;
    for (int it=0; it<ENT_ITERS; ++it){
      dm *= 0.5f;
      float tau = tau_lo + dm;
      float sl = 0.f;
      #pragma unroll
      for (int j=0;j<5;++j){ float pj = pfn(Xs[j]-tau, inv); p[j]=pj; sl += pj; }
      fsum = wsum(sl);
      if ((fsum - 1.f)*f_lo >= 0.f) tau_lo = tau;
    }
    float rs = 1.f/fsum;
    #pragma unroll
    for (int j=0;j<5;++j){ int k = lane + j*64; if (k < 284) saw[k] = p[j]*rs; }
  }
  __syncthreads();
  // --- global_c over x_s (original embeddings, rows 0..283) ---
  float g = 0.f;
  for (int k=0; k<284; ++k) g = fmaf(saw[k], x_[((size_t)b*LQ + k)*256 + t], g);
  gcs[t] = g;
  ms[t]  = ln[((size_t)b*LQ + (LQ-1))*256 + t];
  __syncthreads();
  if (t < 128){
    float acc = wfb[t];
    const float* wr = wfw + (size_t)t*512;
    for (int d=0; d<256; ++d) acc = fmaf(gcs[d], wr[d], acc);
    for (int d=0; d<256; ++d) acc = fmaf(ms[d], wr[256+d], acc);
    const float SC = 1.0507009873554805f, AL = 1.6732632423543772f;
    acc = acc > 0.f ? SC*acc : SC*AL*(expf(acc) - 1.f);
    cb[t] = acc;
  }
  __syncthreads();
  float sq = (t < 128) ? cb[t]*cb[t] : 0.f;
  sq = wsum(sq);
  if ((t&63)==0) red[t>>6] = sq;
  __syncthreads();
  float nrm = rsqrtf(red[0]+red[1]+red[2]+red[3]);
  if (t < 128) l_c[b*128 + t] = cb[t]*nrm;
}

// ---------------- z = 20 * l_c @ normalize(emb_w[1:-1])^T (fp32) ----------------
__global__ __launch_bounds__(256) void k_z(const float* __restrict__ emb, const float* __restrict__ l_c,
    float* __restrict__ z){
  __shared__ float lc[64*128];
  __shared__ float e[64*128];
  __shared__ float invn[64];
  int t = threadIdx.x;
  int i0 = blockIdx.x*64;
  #pragma unroll
  for (int u=0;u<8;++u)
    ((float4*)lc)[t + u*256] = ((const float4*)l_c)[t + u*256];
  #pragma unroll
  for (int pass=0; pass<8; ++pass){
    int r = (t>>5) + pass*8;
    int c = t & 31;
    int gi = i0 + r;
    float4 v = make_float4(0.f,0.f,0.f,0.f);
    if (gi < NOUT) v = ((const float4*)(emb + ((size_t)gi+1)*128))[c];
    ((float4*)e)[r*32 + (c ^ (r&31))] = v;
  }
  __syncthreads();
  {
    int r = t>>2, q = t&3;
    float ss = 0.f;
    #pragma unroll
    for (int u=0;u<8;++u){
      int c = q*8 + u;
      float4 v = ((float4*)e)[r*32 + (c ^ (r&31))];
      ss = fmaf(v.x,v.x, fmaf(v.y,v.y, fmaf(v.z,v.z, fmaf(v.w,v.w, ss))));
    }
    ss += __shfl_xor(ss,1);
    ss += __shfl_xor(ss,2);
    if (q==0) invn[r] = rsqrtf(ss);
  }
  __syncthreads();
  int i = t & 63, bg = t >> 6;
  float inv = invn[i];
  float acc[16];
  #pragma unroll
  for (int u=0;u<16;++u) acc[u]=0.f;
  #pragma unroll 4
  for (int c=0;c<32;++c){
    float4 ev = ((float4*)e)[i*32 + (c ^ (i&31))];
    #pragma unroll
    for (int bb=0; bb<16; ++bb){
      float4 lv = ((float4*)lc)[(bg*16+bb)*32 + c];
      acc[bb] = fmaf(ev.x,lv.x, fmaf(ev.y,lv.y, fmaf(ev.z,lv.z, fmaf(ev.w,lv.w, acc[bb]))));
    }
  }
  int gi = i0 + i;
  if (gi < NOUT){
    float sc = 20.f * inv;
    #pragma unroll
    for (int bb=0; bb<16; ++bb) z[(size_t)(bg*16+bb)*NOUT + gi] = sc*acc[bb];
  }
}

extern "C" void kernel_launch(void* const* d_in, const int* in_sizes, int n_in,
                              void* d_out, int out_size, void* d_ws, size_t ws_size,
                              hipStream_t stream){
  const int*   x          = (const int*)d_in[0];
  const int*   pos        = (const int*)d_in[1];
  const float* emb_w      = (const float*)d_in[2];
  const float* pos_emb_w  = (const float*)d_in[3];
  const float* atten_w0   = (const float*)d_in[4];
  const float* atten_w1   = (const float*)d_in[5];
  const float* atten_w2   = (const float*)d_in[6];
  const float* atten_bias = (const float*)d_in[7];
  const float* mlp_w      = (const float*)d_in[8];
  const float* mlp_b      = (const float*)d_in[9];
  const float* sa_w1_w    = (const float*)d_in[10];
  const float* sa_w1_b    = (const float*)d_in[11];
  const float* sa_w2_w    = (const float*)d_in[12];
  const float* sa_w2_b    = (const float*)d_in[13];
  const float* ln_g       = (const float*)d_in[14];
  const float* ln_b       = (const float*)d_in[15];
  const float* w_f_w      = (const float*)d_in[16];
  const float* w_f_b      = (const float*)d_in[17];
  const float* alpha_w_w  = (const float*)d_in[18];
  const float* alpha_w_b  = (const float*)d_in[19];
  float* z = (float*)d_out;

  float* ws = (float*)d_ws;
  const size_t NX = (size_t)64*LQ*256;   // 4,669,440
  const size_t NS = (size_t)64*LQ*LD_S;  // 5,253,120
  // fp32 region (floats): 3*NX + NS + 43008  ~= 77.2 MB
  float* x_    = ws;                     // [NX] fp32 x_
  float* bq    = ws + NX;                // [NX] t output (fp32)
  float* sc    = ws + 2*NX;              // [NS] scores -> (later) v2/LN in-place
  float* attv  = ws + 2*NX + NS;         // [NX] att_v fp32 (residual)
  float* v2    = sc;                     // alias (scores dead after entmax)
  float* lnb   = v2;                     // alias
  float* small = ws + 3*NX + NS;
  float* a_ent  = small;                 // 64
  float* a_glob = small + 64;            // 64
  float* msw2   = small + 128;           // 16384
  float* albuf  = small + 128 + 16384;   // 64*284
  float* l_c    = albuf + 64*284;        // 8192
  // bf16 region (~48.4 MB). total ws use ~126 MB.
  short* bfbase = (short*)(ws + 3*NX + NS + 43008);
  short* x_bf   = bfbase;                // [NX]
  short* gbf    = bfbase + NX;           // [NX] q_ then h
  short* attbf  = bfbase + 2*NX;         // [NS]
  short* attvbf = attbf + NS;            // [NX]
  short* lnbf   = attvbf + NX;           // [NX]
  short* wbf    = lnbf + NX;             // 4*65536: mlp_w, sa_w1_w, sa_w2_w, atten_w1
  short* w_mlp  = wbf;
  short* w_sa1  = wbf + 65536;
  short* w_sa2  = wbf + 2*65536;
  short* w_aw1  = wbf + 3*65536;

  k_gather<<<18240, 256, 0, stream>>>(x, pos, emb_w, pos_emb_w, x_, x_bf);
  k_castw<<<1024, 256, 0, stream>>>(mlp_w, sa_w1_w, sa_w2_w, atten_w1, wbf);
  k_aent<<<64, 64, 0, stream>>>(x_, alpha_w_w, alpha_w_b, a_ent);
  // q_ = relu(x_ @ mlp_w^T + mlp_b)            -> gbf (bf16 only)
  k_mgemm<true,1,false,true><<<dim3(4,285,1), 256, 0, stream>>>(
      x_bf,256,0,256, w_mlp,256,0, nullptr, gbf,256,0,
      18240,256,256, mlp_b, nullptr, nullptr, 0.f);
  // scores = q_ @ x_^T / 16, key-masked        -> sc (fp32)
  k_mgemm<true,3,true,false><<<dim3(5,5,64), 256, 0, stream>>>(
      gbf,256,(long long)LQ*256,256, x_bf,256,(long long)LQ*256,
      sc, nullptr, LD_S,(long long)LQ*LD_S,
      285,285,256, nullptr, nullptr, x, 0.0625f);
  k_entmax1<<<4560, 256, 0, stream>>>(sc, a_ent, attbf);
  // att_v = att @ x_ (B non-transposed)        -> attv fp32 + attvbf
  k_mgemm<false,0,true,true><<<dim3(4,5,64), 256, 0, stream>>>(
      attbf,LD_S,(long long)LQ*LD_S,LD_S, x_bf,256,(long long)LQ*256,
      attv, attvbf, 256,(long long)LQ*256,
      285,256,285, nullptr, nullptr, nullptr, 0.f);
  // h = relu(att_v @ sa_w1^T + b1)             -> gbf (bf16 only)
  k_mgemm<true,1,false,true><<<dim3(4,285,1), 256, 0, stream>>>(
      attvbf,256,0,256, w_sa1,256,0, nullptr, gbf,256,0,
      18240,256,256, sa_w1_b, nullptr, nullptr, 0.f);
  // v2 = h @ sa_w2^T + b2 + att_v              -> v2 fp32 (aliases sc)
  k_mgemm<true,2,true,false><<<dim3(4,285,1), 256, 0, stream>>>(
      gbf,256,0,256, w_sa2,256,0, v2, nullptr, 256,0,
      18240,256,256, sa_w2_b, attv, nullptr, 0.f);
  k_ln<<<18240, 256, 0, stream>>>(v2, ln_g, ln_b, lnbf);
  k_msw2<<<64, 256, 0, stream>>>(lnb, atten_w2, atten_bias, alpha_w_w, alpha_w_b, msw2, a_glob);
  // t = relu(ln @ atten_w1 + msw2[b]) (B non-transposed) -> bq fp32
  k_mgemm<false,4,true,false><<<dim3(4,285,1), 256, 0, stream>>>(
      lnbf,256,0,256, w_aw1,256,0, bq, nullptr, 256,0,
      18240,256,256, msw2, nullptr, nullptr, 0.f);
  k_al<<<4544, 256, 0, stream>>>(bq, atten_w0, x, albuf);
  k_second<<<64, 256, 0, stream>>>(albuf, a_glob, x_, lnb, w_f_w, w_f_b, l_c);
  k_z<<<1563, 256, 0, stream>>>(emb_w, l_c, z);
}

// Round 9
// 411.003 us; speedup vs baseline: 1.3639x; 1.1236x over previous
//
#include <hip/hip_runtime.h>
#include <hip/hip_bf16.h>
#include <math.h>

#define LQ 285
#define LD_S 288
#define ENT_ITERS 30   // bisection converged below fp32 ulp by ~27; ref's 50 adds nothing
#define NOUT 99999
#define LDK 72   // 64 k + 8 pad (bf16) -> row stride 144B, 2-way bank alias (free)
#define LDZ 136  // 128 k + 8 pad (bf16) for k_z2 tiles

typedef __attribute__((ext_vector_type(8))) short bf16x8;
typedef __attribute__((ext_vector_type(4))) float f32x4;

__device__ __forceinline__ float wsum(float v){
  #pragma unroll
  for (int o=32;o;o>>=1) v += __shfl_xor(v,o);
  return v;
}
__device__ __forceinline__ float wmax(float v){
  #pragma unroll
  for (int o=32;o;o>>=1) v = fmaxf(v, __shfl_xor(v,o));
  return v;
}
// native v_log_f32 (=log2) + v_exp_f32 (=2^x): single-instruction pow, ~1ulp
__device__ __forceinline__ float pfn(float z, float inv){
  return z > 0.f ? __builtin_amdgcn_exp2f(inv * __builtin_amdgcn_logf(z)) : 0.f;
}
__device__ __forceinline__ short f2bf(float f){
  __hip_bfloat16 h = __float2bfloat16(f);
  return *(short*)&h;
}

// ---------------- gather: x_ = concat(emb_w[x], pos_emb_w[pos]), fp32 + bf16 ----------------
__global__ __launch_bounds__(256) void k_gather(const int* __restrict__ x, const int* __restrict__ pos,
    const float* __restrict__ emb, const float* __restrict__ pemb,
    float* __restrict__ xo, short* __restrict__ xbf){
  int bl = blockIdx.x;             // 0..18239
  int d  = threadIdx.x;
  int xi = x[bl], pi = pos[bl];
  float v = (d < 128) ? emb[(size_t)xi*128 + d] : pemb[(size_t)pi*128 + (d-128)];
  xo [(size_t)bl*256 + d] = v;
  xbf[(size_t)bl*256 + d] = f2bf(v);
}

// ---------------- cast 4 weight matrices [256x256] to bf16 ----------------
__global__ __launch_bounds__(256) void k_castw(const float* __restrict__ w0, const float* __restrict__ w1,
    const float* __restrict__ w2, const float* __restrict__ w3, short* __restrict__ dst){
  int idx = blockIdx.x*256 + threadIdx.x;       // 0..262143
  int which = idx >> 16, off = idx & 65535;
  const float* s = which==0 ? w0 : which==1 ? w1 : which==2 ? w2 : w3;
  dst[idx] = f2bf(s[off]);
}

// ---------------- a_ent per batch ----------------
__global__ __launch_bounds__(64) void k_aent(const float* __restrict__ x_, const float* __restrict__ aw,
    const float* __restrict__ ab, float* __restrict__ a_ent){
  int b = blockIdx.x, lane = threadIdx.x;
  const float* r = x_ + ((size_t)b*LQ + (LQ-1))*256;
  float s = 0.f;
  #pragma unroll
  for (int j=0;j<4;++j){ int k = lane + j*64; s = fmaf(r[k], aw[k], s); }
  s = wsum(s);
  if (lane==0){
    float a = 1.f/(1.f + expf(-(s + ab[0]))) + 1.f;
    if (a == 1.f) a = 1.0001f;
    a_ent[b] = a;
  }
}

// ---------------- MFMA bf16 GEMM, 64x64 tile, 4 waves, BK=64 ----------------
// C[M,N] = A[M,K] @ (BT ? B[N,K]^T : B[K,N]); A,B bf16, accum fp32.
// EPI: 0 none | 1 bias+relu | 2 bias+res | 3 scale+key-mask(-inf) | 4 per-row-batch bias + relu
// OF32: write fp32 C; OBF: write bf16 Cbf.
template<bool BT, int EPI, bool OF32, bool OBF>
__global__ __launch_bounds__(256) void k_mgemm(
    const short* __restrict__ A, int lda, long long strA, int kpadA,
    const short* __restrict__ Bm, int ldb, long long strB,
    float* __restrict__ C, short* __restrict__ Cbf, int ldc, long long strC,
    int M, int N, int K,
    const float* __restrict__ bias,
    const float* __restrict__ res,
    const int* __restrict__ xids,
    float scale)
{
  __shared__ __align__(16) short As[64*LDK];
  __shared__ __align__(16) short Bs[64*LDK];
  const int bz = blockIdx.z;
  A  += (size_t)bz * strA;
  Bm += (size_t)bz * strB;
  if (OF32) C   += (size_t)bz * strC;
  if (OBF)  Cbf += (size_t)bz * strC;
  const int* xb = xids ? xids + (size_t)bz*LQ : nullptr;
  const int t  = threadIdx.x;
  const int wv = t >> 6, ln = t & 63;
  const int l16 = ln & 15, kseg = ln >> 4;      // fragment row/col + k-segment
  const int m0 = blockIdx.y*64, n0 = blockIdx.x*64;

  f32x4 acc[4] = {};

  for (int k0 = 0; k0 < K; k0 += 64){
    // --- stage A tile [64 rows][64 k] ---
    #pragma unroll
    for (int it=0; it<2; ++it){
      int idx8 = t + it*256;                    // 0..511
      int r = idx8 >> 3, c8 = (idx8 & 7) << 3;  // row 0..63, k-chunk of 8
      int gr = m0 + r, gk = k0 + c8;
      bf16x8 v = {};
      if (gr < M){
        if (gk + 8 <= kpadA){
          v = *(const bf16x8*)(A + (size_t)gr*lda + gk);
        } else {
          #pragma unroll
          for (int e=0;e<8;++e) if (gk+e < K) v[e] = A[(size_t)gr*lda + gk+e];
        }
      }
      *(bf16x8*)&As[r*LDK + c8] = v;
    }
    // --- stage B tile -> Bs[n][k] ---
    if (BT){
      // B is [N][K] row-major: direct copy
      #pragma unroll
      for (int it=0; it<2; ++it){
        int idx8 = t + it*256;
        int n = idx8 >> 3, c8 = (idx8 & 7) << 3;
        int gn = n0 + n, gk = k0 + c8;
        bf16x8 v = {};
        if (gn < N){
          if (gk + 8 <= K){
            v = *(const bf16x8*)(Bm + (size_t)gn*ldb + gk);
          } else {
            #pragma unroll
            for (int e=0;e<8;++e) if (gk+e < K) v[e] = Bm[(size_t)gn*ldb + gk+e];
          }
        }
        *(bf16x8*)&Bs[n*LDK + c8] = v;
      }
    } else {
      // B is [K][N] row-major: transpose-stage (short2 reads)
      #pragma unroll
      for (int j=0; j<8; ++j){
        int idx2 = t + j*256;                   // 0..2047
        int kk = idx2 >> 5, n2 = (idx2 & 31) << 1;
        int gk = k0 + kk;
        short lo = 0, hi = 0;
        if (gk < K){
          int vv = *(const int*)(Bm + (size_t)gk*ldb + n0 + n2);
          lo = (short)(vv & 0xffff); hi = (short)((unsigned)vv >> 16);
        }
        Bs[(n2  )*LDK + kk] = lo;
        Bs[(n2+1)*LDK + kk] = hi;
      }
    }
    __syncthreads();
    // --- MFMA: wave wv computes rows [wv*16, wv*16+16) x 64 cols ---
    #pragma unroll
    for (int ks=0; ks<64; ks+=32){
      bf16x8 af = *(const bf16x8*)&As[(wv*16 + l16)*LDK + ks + kseg*8];
      #pragma unroll
      for (int ct=0; ct<4; ++ct){
        bf16x8 bf = *(const bf16x8*)&Bs[(ct*16 + l16)*LDK + ks + kseg*8];
        acc[ct] = __builtin_amdgcn_mfma_f32_16x16x32_bf16(af, bf, acc[ct], 0, 0, 0);
      }
    }
    __syncthreads();
  }
  // --- epilogue: C/D layout col=lane&15, row=(lane>>4)*4+i (HW-verified m89/m91) ---
  #pragma unroll
  for (int ct=0; ct<4; ++ct){
    int col = n0 + ct*16 + l16;
    if (col >= N) continue;
    #pragma unroll
    for (int i=0;i<4;++i){
      int row = m0 + wv*16 + kseg*4 + i;
      if (row >= M) continue;
      float v = acc[ct][i];
      if (EPI == 1)      v = fmaxf(v + bias[col], 0.f);
      else if (EPI == 2) v = v + bias[col] + res[(size_t)row*ldc + col];
      else if (EPI == 3){ v *= scale; if (xb[col] == 0) v = -INFINITY; }
      else if (EPI == 4) v = fmaxf(v + bias[(row/LQ)*256 + col], 0.f);
      if (OF32) C  [(size_t)row*ldc + col] = v;
      if (OBF)  Cbf[(size_t)row*ldc + col] = f2bf(v);
    }
  }
}

// ---------------- entmax over 285 keys, one wave per row; fp32 in, bf16 out ----------------
__global__ __launch_bounds__(256) void k_entmax1(const float* __restrict__ att, const float* __restrict__ a_ent,
    short* __restrict__ attbf){
  int wid = blockIdx.x*4 + (threadIdx.x >> 6);
  int lane = threadIdx.x & 63;
  int b = wid / LQ;
  const float* row = att + (size_t)wid * LD_S;
  short* orow = attbf + (size_t)wid * LD_S;
  float alpha = a_ent[b], am1 = alpha - 1.f, inv = 1.f/am1;
  float Xs[5];
  #pragma unroll
  for (int j=0;j<5;++j){ int k = lane + j*64; Xs[j] = (k < LQ) ? row[k]*am1 : -INFINITY; }
  float mx = Xs[0];
  #pragma unroll
  for (int j=1;j<5;++j) mx = fmaxf(mx, Xs[j]);
  mx = wmax(mx);
  float tau_lo = mx - 1.f;
  float tau_hi = mx - __builtin_amdgcn_exp2f(am1 * __builtin_amdgcn_logf(1.f/(float)LQ));
  float s = 0.f;
  #pragma unroll
  for (int j=0;j<5;++j) s += pfn(Xs[j]-tau_lo, inv);
  float f_lo = wsum(s) - 1.f;
  float dm = tau_hi - tau_lo;
  float p[5]; float fsum = 1.f;
  for (int it=0; it<ENT_ITERS; ++it){
    dm *= 0.5f;
    float tau = tau_lo + dm;
    float sl = 0.f;
    #pragma unroll
    for (int j=0;j<5;++j){ float pj = pfn(Xs[j]-tau, inv); p[j]=pj; sl += pj; }
    fsum = wsum(sl);
    if ((fsum - 1.f)*f_lo >= 0.f) tau_lo = tau;
  }
  float rs = 1.f/fsum;
  #pragma unroll
  for (int j=0;j<5;++j){
    int k = lane + j*64;
    if (k < LQ) orow[k] = f2bf(p[j]*rs);
    else if (k < LD_S) orow[k] = 0;   // zero pad: GEMM3 reads through k=287
  }
}

// ---------------- layernorm over 256 (in-place on v2) + bf16 out ----------------
__global__ __launch_bounds__(256) void k_ln(float* __restrict__ v2, const float* __restrict__ g,
    const float* __restrict__ bb, short* __restrict__ obf){
  __shared__ float red[4];
  int r = blockIdx.x, t = threadIdx.x;
  float v = v2[(size_t)r*256 + t];
  float s = wsum(v);
  if ((t&63)==0) red[t>>6] = s;
  __syncthreads();
  float mean = (red[0]+red[1]+red[2]+red[3]) * (1.f/256.f);
  __syncthreads();
  float d = v - mean;
  float ss = wsum(d*d);
  if ((t&63)==0) red[t>>6] = ss;
  __syncthreads();
  float var = (red[0]+red[1]+red[2]+red[3]) * (1.f/256.f);
  float o = d * rsqrtf(var + 1e-5f) * g[t] + bb[t];
  v2[(size_t)r*256 + t] = o;
  obf[(size_t)r*256 + t] = f2bf(o);
}

// ---------------- m_s @ atten_w2 + bias, and a_glob ----------------
__global__ __launch_bounds__(256) void k_msw2(const float* __restrict__ ln, const float* __restrict__ w2,
    const float* __restrict__ abias, const float* __restrict__ aw, const float* __restrict__ ab,
    float* __restrict__ msw2, float* __restrict__ a_glob){
  __shared__ float ms[256];
  __shared__ float red[4];
  int b = blockIdx.x, t = threadIdx.x;
  float m = ln[((size_t)b*LQ + (LQ-1))*256 + t];
  ms[t] = m;
  float s = wsum(m * aw[t]);
  if ((t&63)==0) red[t>>6] = s;
  __syncthreads();
  if (t == 0){
    float dot = red[0]+red[1]+red[2]+red[3] + ab[0];
    float a = 1.f/(1.f + expf(-dot)) + 1.f;
    if (a == 1.f) a = 1.0001f;
    a_glob[b] = a;
  }
  float acc = abias[t];
  for (int d=0; d<256; ++d) acc = fmaf(ms[d], w2[d*256 + t], acc);
  msw2[b*256 + t] = acc;
}

// ---------------- al = t @ atten_w0^T, masked ----------------
__global__ __launch_bounds__(256) void k_al(const float* __restrict__ tbuf, const float* __restrict__ w0,
    const int* __restrict__ x, float* __restrict__ al){
  int wid = blockIdx.x*4 + (threadIdx.x >> 6);
  int lane = threadIdx.x & 63;
  int b = wid / 284, r = wid % 284;
  const float* tr = tbuf + ((size_t)b*LQ + r)*256;
  float s = 0.f;
  #pragma unroll
  for (int j=0;j<4;++j){ int k = lane + j*64; s = fmaf(tr[k], w0[k], s); }
  s = wsum(s);
  if (lane == 0) al[b*284 + r] = (x[b*LQ + r] != 0) ? s : -INFINITY;
}

// ---------------- entmax over 284 (wave-local, no barriers) + global_c + selu head + l_c (bf16) ----------------
__global__ __launch_bounds__(256) void k_second(
    const float* __restrict__ al, const float* __restrict__ a_glob,
    const float* __restrict__ x_, const float* __restrict__ ln,
    const float* __restrict__ wfw, const float* __restrict__ wfb,
    short* __restrict__ lcbf){
  __shared__ float red[4];
  __shared__ float saw[284];
  __shared__ float gcs[256];
  __shared__ float ms[256];
  __shared__ float cb[128];
  int b = blockIdx.x, t = threadIdx.x;
  int wv = t >> 6, lane = t & 63;
  // --- bisection entirely inside wave 0: 5 elems/lane, shuffle reduce, zero barriers ---
  if (wv == 0){
    float alpha = a_glob[b], am1 = alpha - 1.f, inv = 1.f/am1;
    float Xs[5];
    #pragma unroll
    for (int j=0;j<5;++j){ int k = lane + j*64; Xs[j] = (k < 284) ? al[b*284 + k]*am1 : -INFINITY; }
    float mx = Xs[0];
    #pragma unroll
    for (int j=1;j<5;++j) mx = fmaxf(mx, Xs[j]);
    mx = wmax(mx);
    float tau_lo = mx - 1.f;
    float tau_hi = mx - __builtin_amdgcn_exp2f(am1 * __builtin_amdgcn_logf(1.f/284.f));
    float s = 0.f;
    #pragma unroll
    for (int j=0;j<5;++j) s += pfn(Xs[j]-tau_lo, inv);
    float f_lo = wsum(s) - 1.f;
    float dm = tau_hi - tau_lo;
    float p[5]; float fsum = 1.f;
    for (int it=0; it<ENT_ITERS; ++it){
      dm *= 0.5f;
      float tau = tau_lo + dm;
      float sl = 0.f;
      #pragma unroll
      for (int j=0;j<5;++j){ float pj = pfn(Xs[j]-tau, inv); p[j]=pj; sl += pj; }
      fsum = wsum(sl);
      if ((fsum - 1.f)*f_lo >= 0.f) tau_lo = tau;
    }
    float rs = 1.f/fsum;
    #pragma unroll
    for (int j=0;j<5;++j){ int k = lane + j*64; if (k < 284) saw[k] = p[j]*rs; }
  }
  __syncthreads();
  // --- global_c over x_s (original embeddings, rows 0..283) ---
  float g = 0.f;
  for (int k=0; k<284; ++k) g = fmaf(saw[k], x_[((size_t)b*LQ + k)*256 + t], g);
  gcs[t] = g;
  ms[t]  = ln[((size_t)b*LQ + (LQ-1))*256 + t];
  __syncthreads();
  if (t < 128){
    float acc = wfb[t];
    const float* wr = wfw + (size_t)t*512;
    for (int d=0; d<256; ++d) acc = fmaf(gcs[d], wr[d], acc);
    for (int d=0; d<256; ++d) acc = fmaf(ms[d], wr[256+d], acc);
    const float SC = 1.0507009873554805f, AL = 1.6732632423543772f;
    acc = acc > 0.f ? SC*acc : SC*AL*(expf(acc) - 1.f);
    cb[t] = acc;
  }
  __syncthreads();
  float sq = (t < 128) ? cb[t]*cb[t] : 0.f;
  sq = wsum(sq);
  if ((t&63)==0) red[t>>6] = sq;
  __syncthreads();
  float nrm = rsqrtf(red[0]+red[1]+red[2]+red[3]);
  if (t < 128) lcbf[b*128 + t] = f2bf(cb[t]*nrm);
}

// ---------------- z = 20 * l_c @ normalize(emb_w[1:-1])^T via MFMA bf16 ----------------
// M=64 batches, N=64 items/block, K=128. Norm in fp32, operands bf16, accum fp32.
__global__ __launch_bounds__(256) void k_z2(const float* __restrict__ emb, const short* __restrict__ lcbf,
    float* __restrict__ z){
  __shared__ __align__(16) short Ls[64*LDZ];   // l_c   [batch][k]
  __shared__ __align__(16) short Es[64*LDZ];   // items [item][k], normalized
  int t = threadIdx.x;
  int i0 = blockIdx.x*64;
  int r = t >> 2, q = t & 3;                   // row 0..63, col-quarter 0..3 (32 k each)
  // stage Ls from precomputed bf16 l_c
  {
    const short* src = lcbf + r*128 + q*32;
    #pragma unroll
    for (int u=0;u<4;++u)
      *(bf16x8*)&Ls[r*LDZ + q*32 + u*8] = *(const bf16x8*)(src + u*8);
  }
  // stage Es: load fp32 row, 4-lane norm reduce, cast*inv to bf16
  {
    int gi = i0 + r;                           // item index; emb row gi+1
    const float* er = emb + ((size_t)gi+1)*128 + q*32;
    float4 v[8];
    float ss = 0.f;
    #pragma unroll
    for (int u=0;u<8;++u){
      float4 x4 = (gi < NOUT) ? ((const float4*)er)[u] : make_float4(0.f,0.f,0.f,0.f);
      v[u] = x4;
      ss = fmaf(x4.x,x4.x, fmaf(x4.y,x4.y, fmaf(x4.z,x4.z, fmaf(x4.w,x4.w, ss))));
    }
    ss += __shfl_xor(ss,1);
    ss += __shfl_xor(ss,2);
    float inv = rsqrtf(ss);                    // gi>=NOUT rows -> NaN, but their cols are write-guarded
    short sh[32];
    #pragma unroll
    for (int u=0;u<8;++u){
      sh[u*4+0] = f2bf(v[u].x*inv); sh[u*4+1] = f2bf(v[u].y*inv);
      sh[u*4+2] = f2bf(v[u].z*inv); sh[u*4+3] = f2bf(v[u].w*inv);
    }
    #pragma unroll
    for (int u=0;u<4;++u)
      *(bf16x8*)&Es[r*LDZ + q*32 + u*8] = *(const bf16x8*)&sh[u*8];
  }
  __syncthreads();
  int wv = t >> 6, ln = t & 63, l16 = ln & 15, kseg = ln >> 4;
  f32x4 acc[4] = {};
  #pragma unroll
  for (int ks=0; ks<128; ks+=32){
    bf16x8 af = *(const bf16x8*)&Ls[(wv*16 + l16)*LDZ + ks + kseg*8];
    #pragma unroll
    for (int ct=0; ct<4; ++ct){
      bf16x8 bfr = *(const bf16x8*)&Es[(ct*16 + l16)*LDZ + ks + kseg*8];
      acc[ct] = __builtin_amdgcn_mfma_f32_16x16x32_bf16(af, bfr, acc[ct], 0, 0, 0);
    }
  }
  // C/D: col(item)=l16, row(batch)=kseg*4+i per 16-block
  #pragma unroll
  for (int ct=0; ct<4; ++ct){
    int col = i0 + ct*16 + l16;
    if (col >= NOUT) continue;
    #pragma unroll
    for (int i=0;i<4;++i){
      int row = wv*16 + kseg*4 + i;
      z[(size_t)row*NOUT + col] = 20.f * acc[ct][i];
    }
  }
}

extern "C" void kernel_launch(void* const* d_in, const int* in_sizes, int n_in,
                              void* d_out, int out_size, void* d_ws, size_t ws_size,
                              hipStream_t stream){
  const int*   x          = (const int*)d_in[0];
  const int*   pos        = (const int*)d_in[1];
  const float* emb_w      = (const float*)d_in[2];
  const float* pos_emb_w  = (const float*)d_in[3];
  const float* atten_w0   = (const float*)d_in[4];
  const float* atten_w1   = (const float*)d_in[5];
  const float* atten_w2   = (const float*)d_in[6];
  const float* atten_bias = (const float*)d_in[7];
  const float* mlp_w      = (const float*)d_in[8];
  const float* mlp_b      = (const float*)d_in[9];
  const float* sa_w1_w    = (const float*)d_in[10];
  const float* sa_w1_b    = (const float*)d_in[11];
  const float* sa_w2_w    = (const float*)d_in[12];
  const float* sa_w2_b    = (const float*)d_in[13];
  const float* ln_g       = (const float*)d_in[14];
  const float* ln_b       = (const float*)d_in[15];
  const float* w_f_w      = (const float*)d_in[16];
  const float* w_f_b      = (const float*)d_in[17];
  const float* alpha_w_w  = (const float*)d_in[18];
  const float* alpha_w_b  = (const float*)d_in[19];
  float* z = (float*)d_out;

  float* ws = (float*)d_ws;
  const size_t NX = (size_t)64*LQ*256;   // 4,669,440
  const size_t NS = (size_t)64*LQ*LD_S;  // 5,253,120
  // fp32 region (floats): 3*NX + NS + 43008  ~= 77.2 MB
  float* x_    = ws;                     // [NX] fp32 x_
  float* bq    = ws + NX;                // [NX] t output (fp32)
  float* sc    = ws + 2*NX;              // [NS] scores -> (later) v2/LN in-place
  float* attv  = ws + 2*NX + NS;         // [NX] att_v fp32 (residual)
  float* v2    = sc;                     // alias (scores dead after entmax)
  float* lnb   = v2;                     // alias
  float* small = ws + 3*NX + NS;
  float* a_ent  = small;                 // 64
  float* a_glob = small + 64;            // 64
  float* msw2   = small + 128;           // 16384
  float* albuf  = small + 128 + 16384;   // 64*284
  // bf16 region. total ws use ~126 MB.
  short* bfbase = (short*)(ws + 3*NX + NS + 43008);
  short* x_bf   = bfbase;                // [NX]
  short* gbf    = bfbase + NX;           // [NX] q_ then h
  short* attbf  = bfbase + 2*NX;         // [NS]
  short* attvbf = attbf + NS;            // [NX]
  short* lnbf   = attvbf + NX;           // [NX]
  short* wbf    = lnbf + NX;             // 4*65536: mlp_w, sa_w1_w, sa_w2_w, atten_w1
  short* w_mlp  = wbf;
  short* w_sa1  = wbf + 65536;
  short* w_sa2  = wbf + 2*65536;
  short* w_aw1  = wbf + 3*65536;
  short* lcbf   = wbf + 4*65536;         // [64*128] bf16 l_c

  k_gather<<<18240, 256, 0, stream>>>(x, pos, emb_w, pos_emb_w, x_, x_bf);
  k_castw<<<1024, 256, 0, stream>>>(mlp_w, sa_w1_w, sa_w2_w, atten_w1, wbf);
  k_aent<<<64, 64, 0, stream>>>(x_, alpha_w_w, alpha_w_b, a_ent);
  // q_ = relu(x_ @ mlp_w^T + mlp_b)            -> gbf (bf16 only)
  k_mgemm<true,1,false,true><<<dim3(4,285,1), 256, 0, stream>>>(
      x_bf,256,0,256, w_mlp,256,0, nullptr, gbf,256,0,
      18240,256,256, mlp_b, nullptr, nullptr, 0.f);
  // scores = q_ @ x_^T / 16, key-masked        -> sc (fp32)
  k_mgemm<true,3,true,false><<<dim3(5,5,64), 256, 0, stream>>>(
      gbf,256,(long long)LQ*256,256, x_bf,256,(long long)LQ*256,
      sc, nullptr, LD_S,(long long)LQ*LD_S,
      285,285,256, nullptr, nullptr, x, 0.0625f);
  k_entmax1<<<4560, 256, 0, stream>>>(sc, a_ent, attbf);
  // att_v = att @ x_ (B non-transposed)        -> attv fp32 + attvbf
  k_mgemm<false,0,true,true><<<dim3(4,5,64), 256, 0, stream>>>(
      attbf,LD_S,(long long)LQ*LD_S,LD_S, x_bf,256,(long long)LQ*256,
      attv, attvbf, 256,(long long)LQ*256,
      285,256,285, nullptr, nullptr, nullptr, 0.f);
  // h = relu(att_v @ sa_w1^T + b1)             -> gbf (bf16 only)
  k_mgemm<true,1,false,true><<<dim3(4,285,1), 256, 0, stream>>>(
      attvbf,256,0,256, w_sa1,256,0, nullptr, gbf,256,0,
      18240,256,256, sa_w1_b, nullptr, nullptr, 0.f);
  // v2 = h @ sa_w2^T + b2 + att_v              -> v2 fp32 (aliases sc)
  k_mgemm<true,2,true,false><<<dim3(4,285,1), 256, 0, stream>>>(
      gbf,256,0,256, w_sa2,256,0, v2, nullptr, 256,0,
      18240,256,256, sa_w2_b, attv, nullptr, 0.f);
  k_ln<<<18240, 256, 0, stream>>>(v2, ln_g, ln_b, lnbf);
  k_msw2<<<64, 256, 0, stream>>>(lnb, atten_w2, atten_bias, alpha_w_w, alpha_w_b, msw2, a_glob);
  // t = relu(ln @ atten_w1 + msw2[b]) (B non-transposed) -> bq fp32
  k_mgemm<false,4,true,false><<<dim3(4,285,1), 256, 0, stream>>>(
      lnbf,256,0,256, w_aw1,256,0, bq, nullptr, 256,0,
      18240,256,256, msw2, nullptr, nullptr, 0.f);
  k_al<<<4544, 256, 0, stream>>>(bq, atten_w0, x, albuf);
  k_second<<<64, 256, 0, stream>>>(albuf, a_glob, x_, lnb, w_f_w, w_f_b, lcbf);
  k_z2<<<1563, 256, 0, stream>>>(emb_w, lcbf, z);
}